// Round 2
// baseline (1014.817 us; speedup 1.0000x reference)
//
#include <hip/hip_runtime.h>

typedef __bf16 bf16;
typedef __bf16 bf16x8 __attribute__((ext_vector_type(8)));
typedef float floatx4 __attribute__((ext_vector_type(4)));

typedef __attribute__((address_space(1))) const void gvoid_t;
typedef __attribute__((address_space(3))) void lvoid_t;

#define B_DIM 8
#define S_DIM 4096
#define M_DIM 32768
#define CHUNK 128
#define NCHUNK 32

__device__ __forceinline__ void gload_lds16(const bf16* g, bf16* l) {
    __builtin_amdgcn_global_load_lds((gvoid_t*)g, (lvoid_t*)l, 16, 0, 0);
}

__device__ __forceinline__ float gelu_tanh(float x) {
    float x3 = x * x * x;
    return 0.5f * x * (1.0f + tanhf(0.7978845608028654f * (x + 0.044715f * x3)));
}

__device__ __forceinline__ float sigmoidf(float z) {
    return 1.0f / (1.0f + expf(-z));
}

// ---------------- weight transpose (f32 -> bf16, W^T), LDS-tiled ----------------
__global__ void prep_weights(const float* __restrict__ W0, const float* __restrict__ W1,
                             const float* __restrict__ W2, const float* __restrict__ W3,
                             const float* __restrict__ W4, const float* __restrict__ W5,
                             bf16* __restrict__ T0, bf16* __restrict__ T1,
                             bf16* __restrict__ T2, bf16* __restrict__ T3,
                             bf16* __restrict__ T4, bf16* __restrict__ T5) {
    __shared__ float tile[32][33];
    int mz = blockIdx.z;
    const float* W = mz == 0 ? W0 : mz == 1 ? W1 : mz == 2 ? W2 : mz == 3 ? W3 : mz == 4 ? W4 : W5;
    bf16* T = mz == 0 ? T0 : mz == 1 ? T1 : mz == 2 ? T2 : mz == 3 ? T3 : mz == 4 ? T4 : T5;
    int tn = blockIdx.x * 32;
    int tk = blockIdx.y * 32;
    int tx = threadIdx.x & 31, ty = threadIdx.x >> 5;   // ty 0..7
#pragma unroll
    for (int i = 0; i < 4; ++i)
        tile[ty + i * 8][tx] = W[(size_t)(tk + ty + i * 8) * 1024 + tn + tx];
    __syncthreads();
#pragma unroll
    for (int i = 0; i < 4; ++i)
        T[(size_t)(tn + ty + i * 8) * 1024 + tk + tx] = (bf16)tile[tx][ty + i * 8];
}

__global__ void sp_kernel(const float* __restrict__ a_param, float* __restrict__ spbuf) {
    int d = blockIdx.x * 256 + threadIdx.x;
    spbuf[d] = log1pf(expf(a_param[d]));
}

// ---------------- gelu: x (f32) -> xg (bf16) ----------------
__global__ void gelu_kernel(const float* __restrict__ x, bf16* __restrict__ xg) {
    size_t i = (size_t)blockIdx.x * 256 + threadIdx.x;   // over n/4 elements
    float4 v = ((const float4*)x)[i];
    bf16 o0 = (bf16)gelu_tanh(v.x), o1 = (bf16)gelu_tanh(v.y);
    bf16 o2 = (bf16)gelu_tanh(v.z), o3 = (bf16)gelu_tanh(v.w);
    typedef __bf16 bf16x4 __attribute__((ext_vector_type(4)));
    bf16x4 o = {o0, o1, o2, o3};
    ((bf16x4*)xg)[i] = o;
}

// ---------------- GEMM: C[32768 x 1024] = A[32768 x 1024] * Bt[1024 x 1024]^T ----------------
// MODE 0: outf = acc + bias              (u, f32)
// MODE 1: outh = bf16(acc + bias)        (v)
// MODE 2: outh = bf16(-8*sigmoid(acc+bias)*sp[gn])          (log_a)
// MODE 3: outh = bf16(sqrt(-expm1(2*la))*sigmoid(acc+bias)*v)  (scaled_in)
// MODE 4: outf = acc + bias + bias2 + auxf[o]               (final, +x residual)
// MODE 5: outf[o] += acc                                    (final accumulate)
template <int MODE>
__launch_bounds__(256, 2)
__global__ void gemm_k1024(const bf16* __restrict__ A, const bf16* __restrict__ Bt,
                           float* __restrict__ outf, bf16* __restrict__ outh,
                           const float* __restrict__ bias,
                           const float* __restrict__ auxf,
                           const bf16* __restrict__ labuf,
                           const bf16* __restrict__ vbuf,
                           const float* __restrict__ bias2) {
    __shared__ __align__(16) bf16 lsA[128 * 64];
    __shared__ __align__(16) bf16 lsB[128 * 64];
    const int tid = threadIdx.x;
    const int wave = tid >> 6;
    const int lane = tid & 63;
    const int lane15 = lane & 15;
    const int quad = lane >> 4;
    const int wm = wave & 1, wn = wave >> 1;
    const long m0 = (long)(blockIdx.x >> 3) * 128;
    const long n0 = (long)(blockIdx.x & 7) * 128;
    const int r_in = lane >> 3;   // row within 8-row wave issue
    const int cch = lane & 7;     // 16B chunk within row

    floatx4 acc[4][4] = {};

    for (int kt = 0; kt < 16; ++kt) {
        __syncthreads();
#pragma unroll
        for (int i = 0; i < 4; ++i) {
            int rr = (i * 4 + wave) * 8 + r_in;
            int g = cch ^ (rr & 7);   // XOR-swizzled source chunk
            gload_lds16(A + (size_t)(m0 + rr) * 1024 + kt * 64 + g * 8, &lsA[(i * 4 + wave) * 512]);
            gload_lds16(Bt + (size_t)(n0 + rr) * 1024 + kt * 64 + g * 8, &lsB[(i * 4 + wave) * 512]);
        }
        __syncthreads();
#pragma unroll
        for (int kk = 0; kk < 2; ++kk) {
            bf16x8 af[4], bfr[4];
#pragma unroll
            for (int mi = 0; mi < 4; ++mi) {
                int ml = wm * 64 + mi * 16 + lane15;
                af[mi] = *(const bf16x8*)&lsA[ml * 64 + ((kk * 4 + quad) ^ (ml & 7)) * 8];
            }
#pragma unroll
            for (int ni = 0; ni < 4; ++ni) {
                int nl = wn * 64 + ni * 16 + lane15;
                bfr[ni] = *(const bf16x8*)&lsB[nl * 64 + ((kk * 4 + quad) ^ (nl & 7)) * 8];
            }
#pragma unroll
            for (int mi = 0; mi < 4; ++mi)
#pragma unroll
                for (int ni = 0; ni < 4; ++ni)
                    acc[mi][ni] = __builtin_amdgcn_mfma_f32_16x16x32_bf16(af[mi], bfr[ni], acc[mi][ni], 0, 0, 0);
        }
    }

#pragma unroll
    for (int mi = 0; mi < 4; ++mi) {
#pragma unroll
        for (int ni = 0; ni < 4; ++ni) {
            floatx4 v = acc[mi][ni];
            long gn = n0 + wn * 64 + ni * 16 + lane15;
#pragma unroll
            for (int r = 0; r < 4; ++r) {
                long gm = m0 + wm * 64 + mi * 16 + quad * 4 + r;
                size_t o = (size_t)gm * 1024 + gn;
                if (MODE == 0) {
                    outf[o] = v[r] + bias[gn];
                } else if (MODE == 1) {
                    outh[o] = (bf16)(v[r] + bias[gn]);
                } else if (MODE == 2) {
                    float z = v[r] + bias[gn];
                    outh[o] = (bf16)(-8.0f * sigmoidf(z) * auxf[gn]);
                } else if (MODE == 3) {
                    float z = v[r] + bias[gn];
                    float laf = (float)labuf[o];
                    float sc = sqrtf(-expm1f(2.0f * laf)) * sigmoidf(z) * (float)vbuf[o];
                    outh[o] = (bf16)sc;
                } else if (MODE == 4) {
                    outf[o] = v[r] + bias[gn] + bias2[gn] + auxf[o];
                } else {
                    outf[o] += v[r];
                }
            }
        }
    }
}

// ---------------- forward scan (3-pass chunked): h = a*h + u ----------------
__global__ void fscan1(const float* __restrict__ u, const float* __restrict__ a_fwd,
                       float* __restrict__ carry) {
    int d = (blockIdx.x & 3) * 256 + threadIdx.x;
    int c = (blockIdx.x >> 2) & 31;
    int b = blockIdx.x >> 7;
    float a = a_fwd[d];
    const float* up = u + ((size_t)(b * S_DIM + c * CHUNK)) * 1024 + d;
    float h = 0.0f;
#pragma unroll 8
    for (int t = 0; t < CHUNK; ++t) h = fmaf(a, h, up[(size_t)t * 1024]);
    carry[((size_t)c * 8 + b) * 1024 + d] = h;
}
__global__ void fscan2(const float* __restrict__ carry, const float* __restrict__ a_fwd,
                       float* __restrict__ H) {
    int idx = blockIdx.x * 256 + threadIdx.x;   // 8192 chains
    int d = idx & 1023, b = idx >> 10;
    float a = a_fwd[d];
    float aL = a;
#pragma unroll
    for (int i = 0; i < 7; ++i) aL *= aL;       // a^128
    float h = 0.0f;
    for (int c = 0; c < NCHUNK; ++c) {
        size_t o = ((size_t)c * 8 + b) * 1024 + d;
        H[o] = h;
        h = fmaf(aL, h, carry[o]);
    }
}
__global__ void fscan3(const float* __restrict__ u, const float* __restrict__ a_fwd,
                       const float* __restrict__ H, bf16* __restrict__ hf) {
    int d = (blockIdx.x & 3) * 256 + threadIdx.x;
    int c = (blockIdx.x >> 2) & 31;
    int b = blockIdx.x >> 7;
    float a = a_fwd[d];
    const float* up = u + ((size_t)(b * S_DIM + c * CHUNK)) * 1024 + d;
    bf16* op = hf + ((size_t)(b * S_DIM + c * CHUNK)) * 1024 + d;
    float h = H[((size_t)c * 8 + b) * 1024 + d];
#pragma unroll 4
    for (int t = 0; t < CHUNK; ++t) {
        h = fmaf(a, h, up[(size_t)t * 1024]);
        op[(size_t)t * 1024] = (bf16)h;
    }
}

// ---------------- reverse RG-LRU scan (3-pass chunked) ----------------
__global__ void bscan1(const bf16* __restrict__ la, const bf16* __restrict__ sc,
                       float* __restrict__ BL, float* __restrict__ BP) {
    int d = (blockIdx.x & 3) * 256 + threadIdx.x;
    int c = (blockIdx.x >> 2) & 31;
    int b = blockIdx.x >> 7;
    const bf16* lap = la + ((size_t)(b * S_DIM + c * CHUNK)) * 1024 + d;
    const bf16* gp = sc + ((size_t)(b * S_DIM + c * CHUNK)) * 1024 + d;
    float h = 0.0f, slog = 0.0f;
#pragma unroll 4
    for (int t = CHUNK - 1; t >= 0; --t) {
        float laf = (float)lap[(size_t)t * 1024];
        h = fmaf(expf(laf), h, (float)gp[(size_t)t * 1024]);
        slog += laf;
    }
    size_t o = ((size_t)c * 8 + b) * 1024 + d;
    BL[o] = h;
    BP[o] = expf(slog);
}
__global__ void bscan2(const float* __restrict__ BL, const float* __restrict__ BP,
                       float* __restrict__ R) {
    int idx = blockIdx.x * 256 + threadIdx.x;   // 8192 chains
    int d = idx & 1023, b = idx >> 10;
    float r = 0.0f;
    for (int c = NCHUNK - 1; c >= 0; --c) {
        size_t o = ((size_t)c * 8 + b) * 1024 + d;
        R[o] = r;                                // state entering chunk c from the right
        r = fmaf(BP[o], r, BL[o]);
    }
}
__global__ void bscan3(const bf16* __restrict__ la, const bf16* __restrict__ sc,
                       const float* __restrict__ R, bf16* __restrict__ hb) {
    int d = (blockIdx.x & 3) * 256 + threadIdx.x;
    int c = (blockIdx.x >> 2) & 31;
    int b = blockIdx.x >> 7;
    const bf16* lap = la + ((size_t)(b * S_DIM + c * CHUNK)) * 1024 + d;
    const bf16* gp = sc + ((size_t)(b * S_DIM + c * CHUNK)) * 1024 + d;
    bf16* op = hb + ((size_t)(b * S_DIM + c * CHUNK)) * 1024 + d;
    float h = R[((size_t)c * 8 + b) * 1024 + d];
#pragma unroll 4
    for (int t = CHUNK - 1; t >= 0; --t) {
        h = fmaf(expf((float)lap[(size_t)t * 1024]), h, (float)gp[(size_t)t * 1024]);
        op[(size_t)t * 1024] = (bf16)h;
    }
}

extern "C" void kernel_launch(void* const* d_in, const int* in_sizes, int n_in,
                              void* d_out, int out_size, void* d_ws, size_t ws_size,
                              hipStream_t stream) {
    const float* x       = (const float*)d_in[0];
    const float* a_fwd   = (const float*)d_in[1];
    const float* Wf1     = (const float*)d_in[2];
    const float* bf1     = (const float*)d_in[3];
    const float* Wf2     = (const float*)d_in[4];
    const float* bf2     = (const float*)d_in[5];
    const float* Wbx     = (const float*)d_in[6];
    const float* bbx     = (const float*)d_in[7];
    const float* Wgx     = (const float*)d_in[8];
    const float* bgx     = (const float*)d_in[9];
    const float* Wga     = (const float*)d_in[10];
    const float* bga     = (const float*)d_in[11];
    const float* a_param = (const float*)d_in[12];
    const float* Wb2     = (const float*)d_in[13];
    const float* bb2     = (const float*)d_in[14];
    float* out = (float*)d_out;
    (void)in_sizes; (void)n_in; (void)out_size; (void)ws_size;

    // ---- workspace layout (~209 MB total) ----
    char* ws = (char*)d_ws;
    size_t off = 0;
    const size_t WSZ = (size_t)1024 * 1024 * 2;          // 2 MB per transposed weight
    bf16* Wf1t = (bf16*)(ws + off); off += WSZ;
    bf16* Wbxt = (bf16*)(ws + off); off += WSZ;
    bf16* Wgxt = (bf16*)(ws + off); off += WSZ;
    bf16* Wgat = (bf16*)(ws + off); off += WSZ;
    bf16* Wf2t = (bf16*)(ws + off); off += WSZ;
    bf16* Wb2t = (bf16*)(ws + off); off += WSZ;
    float* spbuf = (float*)(ws + off); off += 4096;
    const size_t BSZ = (size_t)M_DIM * 1024 * 2;         // 64 MB bf16 [M][1024]
    bf16* buf0 = (bf16*)(ws + off); off += BSZ;          // xg -> hf
    bf16* buf1 = (bf16*)(ws + off); off += BSZ;          // v  -> hb
    bf16* buf2 = (bf16*)(ws + off); off += BSZ;          // la
    float* Fc = (float*)(ws + off); off += (size_t)NCHUNK * 8 * 1024 * 4;
    float* FH = (float*)(ws + off); off += (size_t)NCHUNK * 8 * 1024 * 4;
    float* BL = (float*)(ws + off); off += (size_t)NCHUNK * 8 * 1024 * 4;
    float* BP = (float*)(ws + off); off += (size_t)NCHUNK * 8 * 1024 * 4;
    float* BR = (float*)(ws + off); off += (size_t)NCHUNK * 8 * 1024 * 4;

    bf16* xg = buf0;
    bf16* hf = buf0;            // xg dead before hf written
    bf16* vb = buf1;
    bf16* hb = buf1;            // v dead before hb written
    bf16* la = buf2;
    float* u = (float*)d_out;   // d_out as f32 scratch (dead before final GEMMs)
    bf16* sc = (bf16*)d_out;    // then as bf16 scratch (dead before final GEMMs)

    // 1. prep: transposed bf16 weights + softplus(a_param)
    prep_weights<<<dim3(32, 32, 6), 256, 0, stream>>>(Wf1, Wbx, Wgx, Wga, Wf2, Wb2,
                                                      Wf1t, Wbxt, Wgxt, Wgat, Wf2t, Wb2t);
    sp_kernel<<<4, 256, 0, stream>>>(a_param, spbuf);
    // 2. gelu
    gelu_kernel<<<32768, 256, 0, stream>>>(x, xg);
    // 3. forward-branch input: u = xg@Wf1 + bf1  (f32, into d_out)
    gemm_k1024<0><<<2048, 256, 0, stream>>>(xg, Wf1t, u, nullptr, bf1, nullptr, nullptr, nullptr, nullptr);
    // 4. backward-branch input: v = xg@Wbx + bbx (bf16)
    gemm_k1024<1><<<2048, 256, 0, stream>>>(xg, Wbxt, nullptr, vb, bbx, nullptr, nullptr, nullptr, nullptr);
    // 5. forward scan -> hf (bf16, overwrites xg)
    fscan1<<<1024, 256, 0, stream>>>(u, a_fwd, Fc);
    fscan2<<<32, 256, 0, stream>>>(Fc, a_fwd, FH);
    fscan3<<<1024, 256, 0, stream>>>(u, a_fwd, FH, hf);
    // 6. gate a: la = -8*sigmoid(v@Wga+bga)*softplus(a_param)   (bf16)
    gemm_k1024<2><<<2048, 256, 0, stream>>>(vb, Wgat, nullptr, la, bga, spbuf, nullptr, nullptr, nullptr);
    // 7. gate x + scaled input: sc = sqrt(-expm1(2la))*sigmoid(v@Wgx+bgx)*v  (bf16, into d_out)
    gemm_k1024<3><<<2048, 256, 0, stream>>>(vb, Wgxt, nullptr, sc, bgx, nullptr, la, vb, nullptr);
    // 8. reverse scan -> hb (bf16, overwrites v)
    bscan1<<<1024, 256, 0, stream>>>(la, sc, BL, BP);
    bscan2<<<32, 256, 0, stream>>>(BL, BP, BR);
    bscan3<<<1024, 256, 0, stream>>>(la, sc, BR, hb);
    // 9. out = hf@Wf2 + bf2 + bb2 + x   (f32, overwrites sc in d_out)
    gemm_k1024<4><<<2048, 256, 0, stream>>>(hf, Wf2t, out, nullptr, bf2, x, nullptr, nullptr, bb2);
    // 10. out += hb@Wb2
    gemm_k1024<5><<<2048, 256, 0, stream>>>(hb, Wb2t, out, nullptr, nullptr, nullptr, nullptr, nullptr, nullptr);
}

// Round 3
// 967.406 us; speedup vs baseline: 1.0490x; 1.0490x over previous
//
#include <hip/hip_runtime.h>

typedef __bf16 bf16;
typedef __bf16 bf16x8 __attribute__((ext_vector_type(8)));
typedef float floatx4 __attribute__((ext_vector_type(4)));

typedef __attribute__((address_space(1))) const void gvoid_t;
typedef __attribute__((address_space(3))) void lvoid_t;

#define B_DIM 8
#define S_DIM 4096
#define M_DIM 32768
#define CHUNK 128
#define NCHUNK 32

__device__ __forceinline__ void gload_lds16(const bf16* g, bf16* l) {
    __builtin_amdgcn_global_load_lds((gvoid_t*)g, (lvoid_t*)l, 16, 0, 0);
}

__device__ __forceinline__ float gelu_tanh(float x) {
    float x3 = x * x * x;
    return 0.5f * x * (1.0f + tanhf(0.7978845608028654f * (x + 0.044715f * x3)));
}

__device__ __forceinline__ float sigmoidf(float z) {
    return 1.0f / (1.0f + expf(-z));
}

// ---------------- weight transpose (f32 -> bf16, W^T), LDS-tiled ----------------
__global__ void prep_weights(const float* __restrict__ W0, const float* __restrict__ W1,
                             const float* __restrict__ W2, const float* __restrict__ W3,
                             const float* __restrict__ W4, const float* __restrict__ W5,
                             bf16* __restrict__ T0, bf16* __restrict__ T1,
                             bf16* __restrict__ T2, bf16* __restrict__ T3,
                             bf16* __restrict__ T4, bf16* __restrict__ T5) {
    __shared__ float tile[32][33];
    int mz = blockIdx.z;
    const float* W = mz == 0 ? W0 : mz == 1 ? W1 : mz == 2 ? W2 : mz == 3 ? W3 : mz == 4 ? W4 : W5;
    bf16* T = mz == 0 ? T0 : mz == 1 ? T1 : mz == 2 ? T2 : mz == 3 ? T3 : mz == 4 ? T4 : T5;
    int tn = blockIdx.x * 32;
    int tk = blockIdx.y * 32;
    int tx = threadIdx.x & 31, ty = threadIdx.x >> 5;   // ty 0..7
#pragma unroll
    for (int i = 0; i < 4; ++i)
        tile[ty + i * 8][tx] = W[(size_t)(tk + ty + i * 8) * 1024 + tn + tx];
    __syncthreads();
#pragma unroll
    for (int i = 0; i < 4; ++i)
        T[(size_t)(tn + ty + i * 8) * 1024 + tk + tx] = (bf16)tile[tx][ty + i * 8];
}

__global__ void sp_kernel(const float* __restrict__ a_param, float* __restrict__ spbuf) {
    int d = blockIdx.x * 256 + threadIdx.x;
    spbuf[d] = log1pf(expf(a_param[d]));
}

// ---------------- gelu: x (f32) -> xg (bf16) ----------------
__global__ void gelu_kernel(const float* __restrict__ x, bf16* __restrict__ xg) {
    size_t i = (size_t)blockIdx.x * 256 + threadIdx.x;   // over n/4 elements
    float4 v = ((const float4*)x)[i];
    bf16 o0 = (bf16)gelu_tanh(v.x), o1 = (bf16)gelu_tanh(v.y);
    bf16 o2 = (bf16)gelu_tanh(v.z), o3 = (bf16)gelu_tanh(v.w);
    typedef __bf16 bf16x4 __attribute__((ext_vector_type(4)));
    bf16x4 o = {o0, o1, o2, o3};
    ((bf16x4*)xg)[i] = o;
}

// ---------------- GEMM: C[32768 x 1024] = A[32768 x 1024] * Bt[1024 x 1024]^T ----------------
// XCD-aware swizzle: blk&7 = XCD (round-robin dispatch); each XCD owns a
// contiguous 32-m-tile range so A rows are fetched by exactly one L2.
// MODE 0: outf = acc + bias              (u, f32)
// MODE 1: outh = bf16(acc + bias)        (v)
// MODE 2: outh = bf16(-8*sigmoid(acc+bias)*sp[gn])          (log_a)
// MODE 3: outh = bf16(sqrt(-expm1(2*la))*sigmoid(acc+bias)*v)  (scaled_in)
// MODE 4: outf = acc + bias + bias2 + auxf[o]               (final, +x residual)
// MODE 5: outf[o] += acc                                    (final accumulate)
template <int MODE>
__launch_bounds__(256, 2)
__global__ void gemm_k1024(const bf16* __restrict__ A, const bf16* __restrict__ Bt,
                           float* __restrict__ outf, bf16* __restrict__ outh,
                           const float* __restrict__ bias,
                           const float* __restrict__ auxf,
                           const bf16* __restrict__ labuf,
                           const bf16* __restrict__ vbuf,
                           const float* __restrict__ bias2) {
    __shared__ __align__(16) bf16 lsA[128 * 64];
    __shared__ __align__(16) bf16 lsB[128 * 64];
    const int tid = threadIdx.x;
    const int wave = tid >> 6;
    const int lane = tid & 63;
    const int lane15 = lane & 15;
    const int quad = lane >> 4;
    const int wm = wave & 1, wn = wave >> 1;
    // XCD-aware swizzle: 2048 blocks = 8 XCDs x 32 m-tiles x 8 n-tiles
    const int blk = blockIdx.x;
    const int xcd = blk & 7;
    const int j = blk >> 3;                   // 0..255, dispatch order within XCD
    const long m0 = (long)(xcd * 32 + (j >> 3)) * 128;
    const long n0 = (long)(j & 7) * 128;
    const int r_in = lane >> 3;   // row within 8-row wave issue
    const int cch = lane & 7;     // 16B chunk within row

    floatx4 acc[4][4] = {};

    for (int kt = 0; kt < 16; ++kt) {
        __syncthreads();
#pragma unroll
        for (int i = 0; i < 4; ++i) {
            int rr = (i * 4 + wave) * 8 + r_in;
            int g = cch ^ (rr & 7);   // XOR-swizzled source chunk
            gload_lds16(A + (size_t)(m0 + rr) * 1024 + kt * 64 + g * 8, &lsA[(i * 4 + wave) * 512]);
            gload_lds16(Bt + (size_t)(n0 + rr) * 1024 + kt * 64 + g * 8, &lsB[(i * 4 + wave) * 512]);
        }
        __syncthreads();
#pragma unroll
        for (int kk = 0; kk < 2; ++kk) {
            bf16x8 af[4], bfr[4];
#pragma unroll
            for (int mi = 0; mi < 4; ++mi) {
                int ml = wm * 64 + mi * 16 + lane15;
                af[mi] = *(const bf16x8*)&lsA[ml * 64 + ((kk * 4 + quad) ^ (ml & 7)) * 8];
            }
#pragma unroll
            for (int ni = 0; ni < 4; ++ni) {
                int nl = wn * 64 + ni * 16 + lane15;
                bfr[ni] = *(const bf16x8*)&lsB[nl * 64 + ((kk * 4 + quad) ^ (nl & 7)) * 8];
            }
#pragma unroll
            for (int mi = 0; mi < 4; ++mi)
#pragma unroll
                for (int ni = 0; ni < 4; ++ni)
                    acc[mi][ni] = __builtin_amdgcn_mfma_f32_16x16x32_bf16(af[mi], bfr[ni], acc[mi][ni], 0, 0, 0);
        }
    }

#pragma unroll
    for (int mi = 0; mi < 4; ++mi) {
#pragma unroll
        for (int ni = 0; ni < 4; ++ni) {
            floatx4 v = acc[mi][ni];
            long gn = n0 + wn * 64 + ni * 16 + lane15;
#pragma unroll
            for (int r = 0; r < 4; ++r) {
                long gm = m0 + wm * 64 + mi * 16 + quad * 4 + r;
                size_t o = (size_t)gm * 1024 + gn;
                if (MODE == 0) {
                    outf[o] = v[r] + bias[gn];
                } else if (MODE == 1) {
                    outh[o] = (bf16)(v[r] + bias[gn]);
                } else if (MODE == 2) {
                    float z = v[r] + bias[gn];
                    outh[o] = (bf16)(-8.0f * sigmoidf(z) * auxf[gn]);
                } else if (MODE == 3) {
                    float z = v[r] + bias[gn];
                    float laf = (float)labuf[o];
                    float sc = sqrtf(-expm1f(2.0f * laf)) * sigmoidf(z) * (float)vbuf[o];
                    outh[o] = (bf16)sc;
                } else if (MODE == 4) {
                    outf[o] = v[r] + bias[gn] + bias2[gn] + auxf[o];
                } else {
                    outf[o] += v[r];
                }
            }
        }
    }
}

// ---------------- forward scan (3-pass chunked): h = a*h + u ----------------
__global__ void fscan1(const float* __restrict__ u, const float* __restrict__ a_fwd,
                       float* __restrict__ carry) {
    int d = (blockIdx.x & 3) * 256 + threadIdx.x;
    int c = (blockIdx.x >> 2) & 31;
    int b = blockIdx.x >> 7;
    float a = a_fwd[d];
    const float* up = u + ((size_t)(b * S_DIM + c * CHUNK)) * 1024 + d;
    float h = 0.0f;
#pragma unroll 8
    for (int t = 0; t < CHUNK; ++t) h = fmaf(a, h, up[(size_t)t * 1024]);
    carry[((size_t)c * 8 + b) * 1024 + d] = h;
}
__global__ void fscan2(const float* __restrict__ carry, const float* __restrict__ a_fwd,
                       float* __restrict__ H) {
    int idx = blockIdx.x * 256 + threadIdx.x;   // 8192 chains
    int d = idx & 1023, b = idx >> 10;
    float a = a_fwd[d];
    float aL = a;
#pragma unroll
    for (int i = 0; i < 7; ++i) aL *= aL;       // a^128
    float h = 0.0f;
    for (int c = 0; c < NCHUNK; ++c) {
        size_t o = ((size_t)c * 8 + b) * 1024 + d;
        H[o] = h;
        h = fmaf(aL, h, carry[o]);
    }
}
__global__ void fscan3(const float* __restrict__ u, const float* __restrict__ a_fwd,
                       const float* __restrict__ H, bf16* __restrict__ hf) {
    int d = (blockIdx.x & 3) * 256 + threadIdx.x;
    int c = (blockIdx.x >> 2) & 31;
    int b = blockIdx.x >> 7;
    float a = a_fwd[d];
    const float* up = u + ((size_t)(b * S_DIM + c * CHUNK)) * 1024 + d;
    bf16* op = hf + ((size_t)(b * S_DIM + c * CHUNK)) * 1024 + d;
    float h = H[((size_t)c * 8 + b) * 1024 + d];
#pragma unroll 4
    for (int t = 0; t < CHUNK; ++t) {
        h = fmaf(a, h, up[(size_t)t * 1024]);
        op[(size_t)t * 1024] = (bf16)h;
    }
}

// ---------------- reverse RG-LRU scan (3-pass chunked) ----------------
__global__ void bscan1(const bf16* __restrict__ la, const bf16* __restrict__ sc,
                       float* __restrict__ BL, float* __restrict__ BP) {
    int d = (blockIdx.x & 3) * 256 + threadIdx.x;
    int c = (blockIdx.x >> 2) & 31;
    int b = blockIdx.x >> 7;
    const bf16* lap = la + ((size_t)(b * S_DIM + c * CHUNK)) * 1024 + d;
    const bf16* gp = sc + ((size_t)(b * S_DIM + c * CHUNK)) * 1024 + d;
    float h = 0.0f, slog = 0.0f;
#pragma unroll 4
    for (int t = CHUNK - 1; t >= 0; --t) {
        float laf = (float)lap[(size_t)t * 1024];
        h = fmaf(expf(laf), h, (float)gp[(size_t)t * 1024]);
        slog += laf;
    }
    size_t o = ((size_t)c * 8 + b) * 1024 + d;
    BL[o] = h;
    BP[o] = expf(slog);
}
__global__ void bscan2(const float* __restrict__ BL, const float* __restrict__ BP,
                       float* __restrict__ R) {
    int idx = blockIdx.x * 256 + threadIdx.x;   // 8192 chains
    int d = idx & 1023, b = idx >> 10;
    float r = 0.0f;
    for (int c = NCHUNK - 1; c >= 0; --c) {
        size_t o = ((size_t)c * 8 + b) * 1024 + d;
        R[o] = r;                                // state entering chunk c from the right
        r = fmaf(BP[o], r, BL[o]);
    }
}
__global__ void bscan3(const bf16* __restrict__ la, const bf16* __restrict__ sc,
                       const float* __restrict__ R, bf16* __restrict__ hb) {
    int d = (blockIdx.x & 3) * 256 + threadIdx.x;
    int c = (blockIdx.x >> 2) & 31;
    int b = blockIdx.x >> 7;
    const bf16* lap = la + ((size_t)(b * S_DIM + c * CHUNK)) * 1024 + d;
    const bf16* gp = sc + ((size_t)(b * S_DIM + c * CHUNK)) * 1024 + d;
    bf16* op = hb + ((size_t)(b * S_DIM + c * CHUNK)) * 1024 + d;
    float h = R[((size_t)c * 8 + b) * 1024 + d];
#pragma unroll 4
    for (int t = CHUNK - 1; t >= 0; --t) {
        h = fmaf(expf((float)lap[(size_t)t * 1024]), h, (float)gp[(size_t)t * 1024]);
        op[(size_t)t * 1024] = (bf16)h;
    }
}

extern "C" void kernel_launch(void* const* d_in, const int* in_sizes, int n_in,
                              void* d_out, int out_size, void* d_ws, size_t ws_size,
                              hipStream_t stream) {
    const float* x       = (const float*)d_in[0];
    const float* a_fwd   = (const float*)d_in[1];
    const float* Wf1     = (const float*)d_in[2];
    const float* bf1     = (const float*)d_in[3];
    const float* Wf2     = (const float*)d_in[4];
    const float* bf2     = (const float*)d_in[5];
    const float* Wbx     = (const float*)d_in[6];
    const float* bbx     = (const float*)d_in[7];
    const float* Wgx     = (const float*)d_in[8];
    const float* bgx     = (const float*)d_in[9];
    const float* Wga     = (const float*)d_in[10];
    const float* bga     = (const float*)d_in[11];
    const float* a_param = (const float*)d_in[12];
    const float* Wb2     = (const float*)d_in[13];
    const float* bb2     = (const float*)d_in[14];
    float* out = (float*)d_out;
    (void)in_sizes; (void)n_in; (void)out_size; (void)ws_size;

    // ---- workspace layout (~209 MB total) ----
    char* ws = (char*)d_ws;
    size_t off = 0;
    const size_t WSZ = (size_t)1024 * 1024 * 2;          // 2 MB per transposed weight
    bf16* Wf1t = (bf16*)(ws + off); off += WSZ;
    bf16* Wbxt = (bf16*)(ws + off); off += WSZ;
    bf16* Wgxt = (bf16*)(ws + off); off += WSZ;
    bf16* Wgat = (bf16*)(ws + off); off += WSZ;
    bf16* Wf2t = (bf16*)(ws + off); off += WSZ;
    bf16* Wb2t = (bf16*)(ws + off); off += WSZ;
    float* spbuf = (float*)(ws + off); off += 4096;
    const size_t BSZ = (size_t)M_DIM * 1024 * 2;         // 64 MB bf16 [M][1024]
    bf16* buf0 = (bf16*)(ws + off); off += BSZ;          // xg -> hf
    bf16* buf1 = (bf16*)(ws + off); off += BSZ;          // v  -> hb
    bf16* buf2 = (bf16*)(ws + off); off += BSZ;          // la
    float* Fc = (float*)(ws + off); off += (size_t)NCHUNK * 8 * 1024 * 4;
    float* FH = (float*)(ws + off); off += (size_t)NCHUNK * 8 * 1024 * 4;
    float* BL = (float*)(ws + off); off += (size_t)NCHUNK * 8 * 1024 * 4;
    float* BP = (float*)(ws + off); off += (size_t)NCHUNK * 8 * 1024 * 4;
    float* BR = (float*)(ws + off); off += (size_t)NCHUNK * 8 * 1024 * 4;

    bf16* xg = buf0;
    bf16* hf = buf0;            // xg dead before hf written
    bf16* vb = buf1;
    bf16* hb = buf1;            // v dead before hb written
    bf16* la = buf2;
    float* u = (float*)d_out;   // d_out as f32 scratch (dead before final GEMMs)
    bf16* sc = (bf16*)d_out;    // then as bf16 scratch (dead before final GEMMs)

    // 1. prep: transposed bf16 weights + softplus(a_param)
    prep_weights<<<dim3(32, 32, 6), 256, 0, stream>>>(Wf1, Wbx, Wgx, Wga, Wf2, Wb2,
                                                      Wf1t, Wbxt, Wgxt, Wgat, Wf2t, Wb2t);
    sp_kernel<<<4, 256, 0, stream>>>(a_param, spbuf);
    // 2. gelu
    gelu_kernel<<<32768, 256, 0, stream>>>(x, xg);
    // 3. forward-branch input: u = xg@Wf1 + bf1  (f32, into d_out)
    gemm_k1024<0><<<2048, 256, 0, stream>>>(xg, Wf1t, u, nullptr, bf1, nullptr, nullptr, nullptr, nullptr);
    // 4. backward-branch input: v = xg@Wbx + bbx (bf16)
    gemm_k1024<1><<<2048, 256, 0, stream>>>(xg, Wbxt, nullptr, vb, bbx, nullptr, nullptr, nullptr, nullptr);
    // 5. forward scan -> hf (bf16, overwrites xg)
    fscan1<<<1024, 256, 0, stream>>>(u, a_fwd, Fc);
    fscan2<<<32, 256, 0, stream>>>(Fc, a_fwd, FH);
    fscan3<<<1024, 256, 0, stream>>>(u, a_fwd, FH, hf);
    // 6. gate a: la = -8*sigmoid(v@Wga+bga)*softplus(a_param)   (bf16)
    gemm_k1024<2><<<2048, 256, 0, stream>>>(vb, Wgat, nullptr, la, bga, spbuf, nullptr, nullptr, nullptr);
    // 7. gate x + scaled input: sc = sqrt(-expm1(2la))*sigmoid(v@Wgx+bgx)*v  (bf16, into d_out)
    gemm_k1024<3><<<2048, 256, 0, stream>>>(vb, Wgxt, nullptr, sc, bgx, nullptr, la, vb, nullptr);
    // 8. reverse scan -> hb (bf16, overwrites v)
    bscan1<<<1024, 256, 0, stream>>>(la, sc, BL, BP);
    bscan2<<<32, 256, 0, stream>>>(BL, BP, BR);
    bscan3<<<1024, 256, 0, stream>>>(la, sc, BR, hb);
    // 9. out = hf@Wf2 + bf2 + bb2 + x   (f32, overwrites sc in d_out)
    gemm_k1024<4><<<2048, 256, 0, stream>>>(hf, Wf2t, out, nullptr, bf2, x, nullptr, nullptr, bb2);
    // 10. out += hb@Wb2
    gemm_k1024<5><<<2048, 256, 0, stream>>>(hb, Wb2t, out, nullptr, nullptr, nullptr, nullptr, nullptr, nullptr);
}